// Round 6
// baseline (74.794 us; speedup 1.0000x reference)
//
#include <hip/hip_runtime.h>
#include <math.h>

// Chamfer distance via MFMA, pred/gt (4,8192,3) fp32 -> scalar.
// d(q,g) = s_q + s_g - 2 q.g as one K=16 fp16 MFMA dot (2-way fp16 split per
// coord; products exact in fp32 accum):
//   q row:  {xh,xh,xl,xl,yh,yh,yl,yl | zh,zh,zl,zl, 1, 1, sh,sl}
//   t row:  {Xh,Xl,Xh,Xl,Yh,Yl,Yh,Yl | Zh,Zl,Zh,Zl,sh,sl, 1, 1}   (X=-2x etc)
// A = 32 targets, B = 32 queries, v_mfma_f32_32x32x16_f16 (layout verified R5/R6).
// R13: R9 counters => ~100 VALU instr per g-iter (VALUBusy 40% @ 532 cyc/g-iter)
// vs ~20 modeled -- fminf lowering (no v_min3 fusion without nnan, canonicalize,
// AGPR moves, R12's rotation copies) made the kernel VALU-instruction-bound
// (~21us of pure VALU issue at 4 waves/SIMD; observed ~24us). Fix: fold in
// INLINE ASM v_min3_f32 (exactly 16 instr/g-iter, inputs finite so min3
// semantics exact); MFMA results pinned to ArchVGPRs; rotation dropped (16
// independent min3 chains need no pipelining). Grid unchanged: NSPLIT=4,
// 1024 blocks = 4 blocks/CU, LDS 68KB/CU, (256,4).

typedef _Float16 half8 __attribute__((ext_vector_type(8)));
typedef float f32x16 __attribute__((ext_vector_type(16)));

#define NPTS   8192
#define TT     512                // targets per LDS chunk (16 KB)
#define NSPLIT 4                  // target splits per cloud
#define SCH    4                  // chunks per split (2048 targets)
#define NQ_TOT 65536              // 2 dirs * 32768 queries

// one guaranteed VOP3 instruction: acc = min(acc, x, y)
#define MIN3(acc, x, y) \
  asm("v_min3_f32 %0, %0, %1, %2" : "+v"(acc) : "v"(x), "v"(y))

__device__ __forceinline__ void split2(float v, _Float16& h, _Float16& l) {
  h = (_Float16)v; l = (_Float16)(v - (float)h);
}

__device__ __forceinline__ void pack_target(float x, float y, float z,
                                            half8& fa, half8& fb) {
  float s = x * x + y * y + z * z;
  _Float16 xh, xl, yh, yl, zh, zl, sh, sl;
  split2(x, xh, xl); split2(y, yh, yl); split2(z, zh, zl); split2(s, sh, sl);
  _Float16 one = (_Float16)1.0f;
  _Float16 Xh = (_Float16)(-2.f * (float)xh), Xl = (_Float16)(-2.f * (float)xl);
  _Float16 Yh = (_Float16)(-2.f * (float)yh), Yl = (_Float16)(-2.f * (float)yl);
  _Float16 Zh = (_Float16)(-2.f * (float)zh), Zl = (_Float16)(-2.f * (float)zl);
  fa = (half8){Xh, Xl, Xh, Xl, Yh, Yl, Yh, Yl};
  fb = (half8){Zh, Zl, Zh, Zl, sh, sl, one, one};
}

__global__ __launch_bounds__(256, 4) void chamfer_mfma(
    const float* __restrict__ pred, const float* __restrict__ gt,
    float* __restrict__ pmin, float* __restrict__ out) {
  __shared__ __align__(16) half8 lds[TT * 2];   // 16 KB, A-frag-linear
  int bid = blockIdx.x;            // 1024 = dir(2) * b(4) * qblk(32) * split(4)
  int split = bid & 3;
  int qblk  = (bid >> 2) & 31;
  int b     = (bid >> 7) & 3;
  int dir   = bid >> 9;            // 0: q=pred t=gt ; 1: q=gt t=pred
  const float* qsrc = dir ? gt : pred;
  const float* tsrc = dir ? pred : gt;
  int t = threadIdx.x, lane = t & 63, wave = t >> 6, ql = lane & 31;
  if (bid == 0 && t == 0) out[0] = 0.f;   // reduce runs strictly after

  // ---- queries: wave handles 64 queries as two B-frags (layout verified) ----
  int qstart = qblk * 256 + wave * 64;
  const float* qb = qsrc + (size_t)(b * NPTS + qstart) * 3;
  float q0x = qb[3 * ql],        q0y = qb[3 * ql + 1],        q0z = qb[3 * ql + 2];
  float q1x = qb[3 * (ql + 32)], q1y = qb[3 * (ql + 32) + 1], q1z = qb[3 * (ql + 32) + 2];
  half8 bq0, bq1;
  {
    float s0 = q0x * q0x + q0y * q0y + q0z * q0z;
    float s1 = q1x * q1x + q1y * q1y + q1z * q1z;
    _Float16 x0h, x0l, y0h, y0l, z0h, z0l, s0h, s0l;
    _Float16 x1h, x1l, y1h, y1l, z1h, z1l, s1h, s1l;
    split2(q0x, x0h, x0l); split2(q0y, y0h, y0l); split2(q0z, z0h, z0l); split2(s0, s0h, s0l);
    split2(q1x, x1h, x1l); split2(q1y, y1h, y1l); split2(q1z, z1h, z1l); split2(s1, s1h, s1l);
    _Float16 one = (_Float16)1.0f;
    bq0 = (lane < 32) ? (half8){x0h, x0h, x0l, x0l, y0h, y0h, y0l, y0l}
                      : (half8){z0h, z0h, z0l, z0l, one, one, s0h, s0l};
    bq1 = (lane < 32) ? (half8){x1h, x1h, x1l, x1l, y1h, y1h, y1l, y1l}
                      : (half8){z1h, z1h, z1l, z1l, one, one, s1h, s1l};
  }

  // ---- target loop: SCH chunks of this split, reg-prefetch double-buffer ----
  const float* tb = tsrc + (size_t)(b * NPTS + split * (SCH * TT)) * 3;
  float p0x, p0y, p0z, p1x, p1y, p1z;
  {
    const float* s0 = tb + (size_t)t * 3;
    const float* s1 = tb + (size_t)(t + 256) * 3;
    p0x = s0[0]; p0y = s0[1]; p0z = s0[2];
    p1x = s1[0]; p1y = s1[1]; p1z = s1[2];
  }

  // persistent vector-min accumulators: 16 independent v_min3 chains
  float vacc0[8], vacc1[8];
  #pragma unroll
  for (int j = 0; j < 8; ++j) { vacc0[j] = INFINITY; vacc1[j] = INFINITY; }

  f32x16 zero = {};
  for (int tc = 0; tc < SCH; ++tc) {
    half8 f0a, f0b, f1a, f1b;
    pack_target(p0x, p0y, p0z, f0a, f0b);
    pack_target(p1x, p1y, p1z, f1a, f1b);
    if (tc) __syncthreads();           // prior chunk's reads done before overwrite
    // A-frag-linear: point k -> lds[(k>>5)*64 + (k&31)] (+32 for frag row 1)
    int base0 = (t >> 5) * 64 + (t & 31);
    lds[base0]            = f0a;
    lds[base0 + 32]       = f0b;
    lds[base0 + 512]      = f1a;       // point t+256 lands 8 tiles later
    lds[base0 + 512 + 32] = f1b;
    if (tc + 1 < SCH) {                // prefetch next chunk during compute
      const float* s0 = tb + (size_t)((tc + 1) * TT + t) * 3;
      const float* s1 = tb + (size_t)((tc + 1) * TT + t + 256) * 3;
      p0x = s0[0]; p0y = s0[1]; p0z = s0[2];
      p1x = s1[0]; p1y = s1[1]; p1z = s1[2];
    }
    __syncthreads();

    #pragma unroll
    for (int g = 0; g < TT / 32; ++g) {
      half8 a = lds[g * 64 + lane];    // lane-contiguous: zero bank conflicts
      f32x16 d0 = __builtin_amdgcn_mfma_f32_32x32x16_f16(a, bq0, zero, 0, 0, 0);
      f32x16 d1 = __builtin_amdgcn_mfma_f32_32x32x16_f16(a, bq1, zero, 0, 0, 0);
      asm("" : "+v"(d0), "+v"(d1));    // results in ArchVGPRs, no AGPR moves
      #pragma unroll
      for (int j = 0; j < 8; ++j) {    // exactly 16 v_min3_f32, all independent
        MIN3(vacc0[j], d0[2 * j], d0[2 * j + 1]);
        MIN3(vacc1[j], d1[2 * j], d1[2 * j + 1]);
      }
    }
  }
  // end-of-wave tree fold (once, amortized over 128 MFMAs)
  float a0 = fminf(fminf(vacc0[0], vacc0[1]), vacc0[2]);
  float a1 = fminf(fminf(vacc0[3], vacc0[4]), vacc0[5]);
  float a2 = fminf(vacc0[6], vacc0[7]);
  float m0 = fminf(fminf(a0, a1), a2);
  float b0 = fminf(fminf(vacc1[0], vacc1[1]), vacc1[2]);
  float b1 = fminf(fminf(vacc1[3], vacc1[4]), vacc1[5]);
  float b2 = fminf(vacc1[6], vacc1[7]);
  float m1 = fminf(fminf(b0, b1), b2);
  // lane^32 holds the other 16 target rows of each tile
  m0 = fminf(m0, __shfl_xor(m0, 32, 64));
  m1 = fminf(m1, __shfl_xor(m1, 32, 64));

  // ---- plain coalesced store of this split's partial mins ----
  if (lane < 32) {
    size_t qi = (size_t)dir * 32768 + (size_t)b * NPTS + qstart + ql;
    pmin[(size_t)split * NQ_TOT + qi]      = m0;
    pmin[(size_t)split * NQ_TOT + qi + 32] = m1;
  }
}

__global__ __launch_bounds__(256) void reduce_kernel(
    const float* __restrict__ pmin, float* __restrict__ out) {
  __shared__ float wsum[4];
  float acc = 0.f;
  for (int i = blockIdx.x * 256 + threadIdx.x; i < NQ_TOT; i += 64 * 256) {
    float v = pmin[i];
    #pragma unroll
    for (int s = 1; s < NSPLIT; ++s) v = fminf(v, pmin[(size_t)s * NQ_TOT + i]);
    acc += fmaxf(v, 0.f);
  }
  acc *= (1.0f / 32768.0f);
  #pragma unroll
  for (int off = 32; off > 0; off >>= 1) acc += __shfl_down(acc, off, 64);
  int wid = threadIdx.x >> 6;
  if ((threadIdx.x & 63) == 0) wsum[wid] = acc;
  __syncthreads();
  if (threadIdx.x == 0) atomicAdd(out, wsum[0] + wsum[1] + wsum[2] + wsum[3]);
}

extern "C" void kernel_launch(void* const* d_in, const int* in_sizes, int n_in,
                              void* d_out, int out_size, void* d_ws, size_t ws_size,
                              hipStream_t stream) {
  const float* pred = (const float*)d_in[0];
  const float* gt   = (const float*)d_in[1];
  float* out = (float*)d_out;
  float* pmin = (float*)d_ws;         // 4 * 65536 * 4 B = 1 MB partial mins

  chamfer_mfma<<<1024, 256, 0, stream>>>(pred, gt, pmin, out);
  reduce_kernel<<<64, 256, 0, stream>>>(pmin, out);
}